// Round 9
// baseline (282.637 us; speedup 1.0000x reference)
//
#include <hip/hip_runtime.h>

typedef unsigned short u16;
typedef __bf16 bf16x8 __attribute__((ext_vector_type(8)));
typedef float f32x4 __attribute__((ext_vector_type(4)));

#define D 64
#define APITCH 72    // sA pitch: 64 agg cols + 8 pad (bf16)
#define LPITCH 136   // sB pitch: 128 + 8 bf16 pad
#define CHUNKS 1024  // edge-array partitions (4 blocks/CU, 512 thr each)
#define BSHIFT 9     // 512 nodes per bucket (nbuck = 196 for N = 100000; max 512)
#define CAPB 10240   // padded per-bucket staging capacity (mean 8163, +23 sigma)
#define CCAP 1152    // LDS edge-list capacity per 64-node tile (mean ~1024, +4 sigma)

__device__ __forceinline__ float b2f(u16 u) {
    unsigned v = ((unsigned)u) << 16;
    float f;
    __builtin_memcpy(&f, &v, 4);
    return f;
}
__device__ __forceinline__ float u2f_lo(unsigned u) {
    unsigned v = u << 16;
    float f;
    __builtin_memcpy(&f, &v, 4);
    return f;
}
__device__ __forceinline__ float u2f_hi(unsigned u) {
    unsigned v = u & 0xFFFF0000u;
    float f;
    __builtin_memcpy(&f, &v, 4);
    return f;
}
__device__ __forceinline__ u16 f2b(float f) {
    unsigned u;
    __builtin_memcpy(&u, &f, 4);
    u = u + 0x7FFFu + ((u >> 16) & 1u);   // RNE
    return (u16)(u >> 16);
}
__device__ __forceinline__ bf16x8 ld_frag(const u16* p) {
    union { uint4 u; bf16x8 b; } cv;
    cv.u = *(const uint4*)p;
    return cv.b;
}
__device__ __forceinline__ bf16x8 ld_frag_u(uint4 u) {
    union { uint4 u; bf16x8 b; } cv;
    cv.u = u;
    return cv.b;
}

// ---------------- binAB: hist -> bulk-reserve (1 atomic per block,bucket) -> scatter
// Staging is PADDED: bucket b owns [b*CAPB, (b+1)*CAPB). Within-bucket order =
// arrival order (valid: segment-sum order unspecified). cvt/weight tails folded in.
__global__ __launch_bounds__(512) void binAB_kernel(
    const int* __restrict__ src, const int* __restrict__ dst, int E,
    int* __restrict__ gcnt,          // [nbuck], zeroed before launch
    int* __restrict__ staging,       // [nbuck*CAPB]
    const float* __restrict__ xf, u16* __restrict__ xb, int total4,
    const float* __restrict__ wl, const float* __restrict__ wr,
    const float* __restrict__ wres, const float* __restrict__ wfc,
    u16* __restrict__ WtL, u16* __restrict__ WresT, u16* __restrict__ WfcT,
    int nbuck, int eper) {
    __shared__ int hist[512];
    __shared__ int cur[512];
    int t = threadIdx.x;
    int c = blockIdx.x;
    int gid = c * 512 + t;
    int gstr = CHUNKS * 512;
    int beg = c * eper, end = min(beg + eper, E);

    hist[t] = 0;
    __syncthreads();
    // pass 1: chunk histogram (dst chunk ~6KB -> stays L1-hot for pass 2)
    for (int i = beg + t; i < end; i += 512)
        atomicAdd(&hist[dst[i] >> BSHIFT], 1);

    // tails (independent of hist; consumed by later dispatches)
    for (int i = gid; i < total4; i += gstr) {
        float4 v = *(const float4*)(xf + i * 4);
        ushort4 o;
        o.x = f2b(v.x); o.y = f2b(v.y); o.z = f2b(v.z); o.w = f2b(v.w);
        *(ushort4*)(xb + i * 4) = o;
    }
    for (int idx = gid; idx < 3 * 64 * 128; idx += gstr) {
        int l = idx >> 13;
        int rem = idx & 8191;
        int n = rem >> 7;
        int k = rem & 127;
        float v = (k < 64) ? wl[l * 4096 + k * 64 + n] : wr[l * 4096 + (k - 64) * 64 + n];
        WtL[idx] = f2b(v);
    }
    for (int idx = gid; idx < 4096; idx += gstr) {
        int n = idx >> 6, k = idx & 63;
        WresT[idx] = f2b(wres[k * 64 + n]);
        WfcT[idx] = f2b(wfc[k * 64 + n]);
    }
    __syncthreads();

    // bulk reservation: one global atomic per non-empty (block,bucket)
    for (int b = t; b < nbuck; b += 512) {
        int cnt = hist[b];
        int base = 0;
        if (cnt > 0) base = atomicAdd(&gcnt[b], cnt);
        cur[b] = b * CAPB + base;
    }
    __syncthreads();

    // pass 2: scatter packed (src | dlow<<17) into reserved cells
    const int mask = (1 << BSHIFT) - 1;
    for (int i = beg + t; i < end; i += 512) {
        int d = dst[i];
        int b = d >> BSHIFT;
        int p = atomicAdd(&cur[b], 1);
        if (p < (b + 1) * CAPB)                // overflow guard (prob ~0)
            staging[p] = src[i] | ((d & mask) << 17);
    }
}

// ---------------- binC: per-bucket degree hist + scan + col scatter (LDS only) ------
// 1024 threads/block (16 waves/CU): the two 8K LDS-atomic passes need concurrency.
__global__ __launch_bounds__(1024) void binC_kernel(const int* __restrict__ staging,
                                                    const int* __restrict__ T,
                                                    int* __restrict__ row_ptr,
                                                    float* __restrict__ inv_deg,
                                                    int* __restrict__ col, int N, int nbuck) {
    __shared__ int cnt[512];
    __shared__ int lrp[512];
    __shared__ int sm[512];
    __shared__ int span[2];
    int b = blockIdx.x;
    int t = threadIdx.x;
    // compact bucket base via scan of clamped T over 512 slots (threads t<512)
    int h = 0;
    if (t < 512) {
        h = (t < nbuck) ? min(T[t], CAPB) : 0;
        sm[t] = h;
    }
    __syncthreads();
    for (int off = 1; off < 512; off <<= 1) {
        int v = (t < 512 && t >= off) ? sm[t - off] : 0;
        __syncthreads();
        if (t < 512) sm[t] += v;
        __syncthreads();
    }
    if (t == b) { span[0] = sm[t] - h; span[1] = sm[t]; }   // b < nbuck <= 512
    if (b == 0 && t == 511) row_ptr[N] = sm[511];           // compact total (== E)
    if (t < 512) cnt[t] = 0;
    __syncthreads();
    int sbeg = span[0];
    int scount = span[1] - span[0];
    int pbeg = b * CAPB;
    int node0 = b << BSHIFT;
    int nn = min(1 << BSHIFT, N - node0);
    for (int i = t; i < scount; i += 1024)
        atomicAdd(&cnt[staging[pbeg + i] >> 17], 1);
    __syncthreads();
    int c0 = 0;
    if (t < 512) {
        c0 = cnt[t];
        sm[t] = c0;
    }
    __syncthreads();
    for (int off = 1; off < 512; off <<= 1) {
        int v = (t < 512 && t >= off) ? sm[t - off] : 0;
        __syncthreads();
        if (t < 512) sm[t] += v;
        __syncthreads();
    }
    if (t < 512) lrp[t] = sm[t] - c0;   // exclusive
    __syncthreads();
    if (t < nn) {
        row_ptr[node0 + t] = sbeg + lrp[t];
        inv_deg[node0 + t] = c0 > 0 ? 1.0f / (float)c0 : 0.0f;
    }
    __syncthreads();
    for (int i = t; i < scount; i += 1024) {
        int word = staging[pbeg + i];
        int ld = word >> 17;
        int k = atomicSub(&cnt[ld], 1) - 1;
        col[sbeg + lrp[ld] + k] = word & 0x1FFFF;
    }
}

// ---------------- fused SAGE layer: gather-mean + GEMM + LN + ReLU + residual --------
// R9 static-slot gather + LDS edge-list (lcol) + sB-staged weights (R6 lesson).
// x GEMM-frags in registers (xa, per-lane-private); epilogue residual read DIRECTLY
// from global behind an explicit branch (R8 lesson: no uninitialized-array ternary;
// rows are L1-hot from the xa loads). LDS 40960 -> 32256 => 5 blocks/CU (was 4).
// NOTE (R3 lesson): LDS f32-atomic aggregation is ~13x slower; register
// slot-accumulation + per-node-sorted col is the fast structure.
__global__ __launch_bounds__(256, 5) void layer_kernel(const u16* __restrict__ xb_in,
                                                       const int* __restrict__ row_ptr,
                                                       const int* __restrict__ col,
                                                       const float* __restrict__ inv_deg,
                                                       const u16* __restrict__ Wt,    // [64][128]
                                                       const float* __restrict__ bl,
                                                       const float* __restrict__ gam,
                                                       const float* __restrict__ bet,
                                                       const u16* __restrict__ WresT, // [64][64]
                                                       const float* __restrict__ bres,
                                                       const u16* __restrict__ WfcT,  // [64][64]
                                                       const float* __restrict__ bfc,
                                                       u16* __restrict__ xb_out,
                                                       float* __restrict__ fout,
                                                       int N, int layer0, int final_) {
    __shared__ __align__(16) u16 sA[64 * APITCH];   // 9216 B: agg -> LN+res output
    __shared__ __align__(16) u16 sB[64 * LPITCH];   // 17408 B: weights; f32 stage in final
    __shared__ int lcol[CCAP];
    __shared__ int rp[65];
    __shared__ float ideg[64];
    int tid = threadIdx.x;
    int base = blockIdx.x * 64;
    int lane = tid & 63;
    int w = tid >> 6;
    int q = lane >> 4;
    int ln = lane & 15;

    // prologue: this lane's x GEMM-frags (A cols 64..127 of K=128), hidden under gather
    uint4 xa[2] = {make_uint4(0, 0, 0, 0), make_uint4(0, 0, 0, 0)};
    {
        int arow = base + w * 16 + ln;
        if (arow < N) {
            xa[0] = *(const uint4*)(xb_in + (size_t)arow * D + q * 8);
            xa[1] = *(const uint4*)(xb_in + (size_t)arow * D + 32 + q * 8);
        }
    }

    // stage B (W^T rows), 4 uint4 per thread
#pragma unroll
    for (int i = 0; i < 4; i++) {
        int idx = i * 256 + tid;
        int r = idx >> 4, c = idx & 15;
        *(uint4*)&sB[r * LPITCH + c * 8] = *(const uint4*)(Wt + idx * 8);
    }
    if (tid < 65) rp[tid] = row_ptr[min(base + tid, N)];
    if (tid < 64) ideg[tid] = (base + tid < N) ? inv_deg[base + tid] : 0.f;
    __syncthreads();

    int e0 = rp[0];
    int tileE = rp[64] - e0;
    bool fits = tileE <= CCAP;
    if (fits) {
        for (int i = tid; i < tileE; i += 256) lcol[i] = col[e0 + i];
    }
    __syncthreads();

    // gather stage: slot-per-node, 2 rounds x 8 slots per wave = 16 nodes/wave
    int slot = lane >> 3;
    int chunk = lane & 7;
    auto run_gather = [&](auto LD) {
#pragma unroll
        for (int r = 0; r < 2; r++) {
            int node_l = w * 16 + r * 8 + slot;
            float a0 = 0, a1 = 0, a2 = 0, a3 = 0, a4 = 0, a5 = 0, a6 = 0, a7 = 0;
            int e = rp[node_l], end = rp[node_l + 1];
#define ACC(v)                                          \
    a0 += u2f_lo(v.x); a1 += u2f_hi(v.x);               \
    a2 += u2f_lo(v.y); a3 += u2f_hi(v.y);               \
    a4 += u2f_lo(v.z); a5 += u2f_hi(v.z);               \
    a6 += u2f_lo(v.w); a7 += u2f_hi(v.w);
            for (; e + 7 < end; e += 8) {
                int s0 = LD(e),     s1 = LD(e + 1), s2 = LD(e + 2), s3 = LD(e + 3);
                int s4 = LD(e + 4), s5 = LD(e + 5), s6 = LD(e + 6), s7 = LD(e + 7);
                uint4 v0 = *(const uint4*)(xb_in + s0 * D + chunk * 8);
                uint4 v1 = *(const uint4*)(xb_in + s1 * D + chunk * 8);
                uint4 v2 = *(const uint4*)(xb_in + s2 * D + chunk * 8);
                uint4 v3 = *(const uint4*)(xb_in + s3 * D + chunk * 8);
                uint4 v4 = *(const uint4*)(xb_in + s4 * D + chunk * 8);
                uint4 v5 = *(const uint4*)(xb_in + s5 * D + chunk * 8);
                uint4 v6 = *(const uint4*)(xb_in + s6 * D + chunk * 8);
                uint4 v7 = *(const uint4*)(xb_in + s7 * D + chunk * 8);
                ACC(v0) ACC(v1) ACC(v2) ACC(v3)
                ACC(v4) ACC(v5) ACC(v6) ACC(v7)
            }
            if (e + 3 < end) {
                int s0 = LD(e), s1 = LD(e + 1), s2 = LD(e + 2), s3 = LD(e + 3);
                uint4 v0 = *(const uint4*)(xb_in + s0 * D + chunk * 8);
                uint4 v1 = *(const uint4*)(xb_in + s1 * D + chunk * 8);
                uint4 v2 = *(const uint4*)(xb_in + s2 * D + chunk * 8);
                uint4 v3 = *(const uint4*)(xb_in + s3 * D + chunk * 8);
                ACC(v0) ACC(v1) ACC(v2) ACC(v3)
                e += 4;
            }
            if (e + 1 < end) {
                int s0 = LD(e), s1 = LD(e + 1);
                uint4 v0 = *(const uint4*)(xb_in + s0 * D + chunk * 8);
                uint4 v1 = *(const uint4*)(xb_in + s1 * D + chunk * 8);
                ACC(v0) ACC(v1)
                e += 2;
            }
            if (e < end) {
                int s0 = LD(e);
                uint4 v0 = *(const uint4*)(xb_in + s0 * D + chunk * 8);
                ACC(v0)
            }
#undef ACC
            float m = ideg[node_l];
            uint4 o;
            o.x = (unsigned)f2b(a0 * m) | ((unsigned)f2b(a1 * m) << 16);
            o.y = (unsigned)f2b(a2 * m) | ((unsigned)f2b(a3 * m) << 16);
            o.z = (unsigned)f2b(a4 * m) | ((unsigned)f2b(a5 * m) << 16);
            o.w = (unsigned)f2b(a6 * m) | ((unsigned)f2b(a7 * m) << 16);
            *(uint4*)&sA[node_l * APITCH + chunk * 8] = o;
        }
    };
    if (fits) run_gather([&](int e) { return lcol[e - e0]; });
    else      run_gather([&](int e) { return col[e]; });
    __syncthreads();

    // GEMM stage: A = [agg (sA cols 0..63) | x (xa regs)], K = 128
    f32x4 acc[4] = {{0, 0, 0, 0}, {0, 0, 0, 0}, {0, 0, 0, 0}, {0, 0, 0, 0}};
    f32x4 accr[4] = {{0, 0, 0, 0}, {0, 0, 0, 0}, {0, 0, 0, 0}, {0, 0, 0, 0}};
    const u16* aRow = &sA[(w * 16 + ln) * APITCH];

#pragma unroll
    for (int c = 0; c < 4; c++) {
        bf16x8 a = (c < 2) ? ld_frag(&aRow[c * 32 + q * 8]) : ld_frag_u(xa[c - 2]);
#pragma unroll
        for (int t = 0; t < 4; t++) {
            bf16x8 b = ld_frag(&sB[(t * 16 + ln) * LPITCH + c * 32 + q * 8]);
            acc[t] = __builtin_amdgcn_mfma_f32_16x16x32_bf16(a, b, acc[t], 0, 0, 0);
        }
    }
    if (layer0) {                       // residual = x @ w_res (same xa frags)
#pragma unroll
        for (int c = 0; c < 2; c++) {
            bf16x8 a = ld_frag_u(xa[c]);
#pragma unroll
            for (int t = 0; t < 4; t++) {
                bf16x8 b = ld_frag(WresT + (t * 16 + ln) * 64 + c * 32 + q * 8);
                accr[t] = __builtin_amdgcn_mfma_f32_16x16x32_bf16(a, b, accr[t], 0, 0, 0);
            }
        }
    }

    float bcol[4], gcol[4], btcol[4], brcol[4];
#pragma unroll
    for (int t = 0; t < 4; t++) {
        int colI = t * 16 + ln;
        bcol[t] = bl[colI];
        gcol[t] = gam[colI];
        btcol[t] = bet[colI];
        brcol[t] = layer0 ? bres[colI] : 0.f;
    }
#pragma unroll
    for (int t = 0; t < 4; t++)
#pragma unroll
        for (int r = 0; r < 4; r++) acc[t][r] += bcol[t];

    float ps[4], pq[4];
#pragma unroll
    for (int r = 0; r < 4; r++) {
        float s = 0, s2 = 0;
#pragma unroll
        for (int t = 0; t < 4; t++) { float h = acc[t][r]; s += h; s2 += h * h; }
        ps[r] = s; pq[r] = s2;
    }
    for (int off = 1; off < 16; off <<= 1) {
#pragma unroll
        for (int r = 0; r < 4; r++) {
            ps[r] += __shfl_xor(ps[r], off, 64);
            pq[r] += __shfl_xor(pq[r], off, 64);
        }
    }
    // epilogue -> sA cols 0..63 (wave-local rows; in-wave LDS dep, no barrier)
#pragma unroll
    for (int r = 0; r < 4; r++) {
        int nb = w * 16 + q * 4 + r;
        int node = base + nb;
        float mu = ps[r] * (1.f / 64.f);
        float var = pq[r] * (1.f / 64.f) - mu * mu;
        var = var < 0.f ? 0.f : var;
        float rstd = rsqrtf(var + 1e-5f);
#pragma unroll
        for (int t = 0; t < 4; t++) {
            int colI = t * 16 + ln;
            float hn = (acc[t][r] - mu) * rstd * gcol[t] + btcol[t];
            hn = hn > 0.f ? hn : 0.f;
            float res;
            if (layer0) {
                res = accr[t][r] + brcol[t];
            } else {
                res = (node < N) ? b2f(xb_in[(size_t)node * D + colI]) : 0.f;
            }
            sA[nb * APITCH + colI] = f2b(hn + res);
        }
    }

    if (final_) {
        // FC: out = x3 @ w_fc + b_fc; stage f32 through sB (dead after GEMM) for
        // coalesced float4 writeback. Pitch 68 floats breaks bank aliasing.
        f32x4 accf[4] = {{0, 0, 0, 0}, {0, 0, 0, 0}, {0, 0, 0, 0}, {0, 0, 0, 0}};
#pragma unroll
        for (int c = 0; c < 2; c++) {
            bf16x8 a = ld_frag(&aRow[c * 32 + q * 8]);
#pragma unroll
            for (int t = 0; t < 4; t++) {
                bf16x8 b = ld_frag(WfcT + (t * 16 + ln) * 64 + c * 32 + q * 8);
                accf[t] = __builtin_amdgcn_mfma_f32_16x16x32_bf16(a, b, accf[t], 0, 0, 0);
            }
        }
        __syncthreads();               // all waves done reading sB
        float* fB = (float*)sB;        // 64 rows x pitch 68 = 4352 floats = 17408 B
#pragma unroll
        for (int r = 0; r < 4; r++) {
            int nb = w * 16 + q * 4 + r;
#pragma unroll
            for (int t = 0; t < 4; t++) {
                int colI = t * 16 + ln;
                fB[nb * 68 + colI] = accf[t][r] + bfc[colI];
            }
        }
        __syncthreads();
#pragma unroll
        for (int i = 0; i < 4; i++) {
            int idx = i * 256 + tid;
            int row = idx >> 4, cc = idx & 15;
            int node = base + row;
            if (node < N)
                *(float4*)(fout + node * D + cc * 4) = *(const float4*)&fB[row * 68 + cc * 4];
        }
    } else {
        // coalesced writeback of this wave's 16 rows (2 uint4 per thread)
#pragma unroll
        for (int i = 0; i < 2; i++) {
            int idx = i * 64 + lane;
            int row = w * 16 + (idx >> 3);
            int ch = idx & 7;
            int node = base + row;
            if (node < N)
                *(uint4*)(xb_out + node * D + ch * 8) = *(const uint4*)&sA[row * APITCH + ch * 8];
        }
    }
}

extern "C" void kernel_launch(void* const* d_in, const int* in_sizes, int n_in,
                              void* d_out, int out_size, void* d_ws, size_t ws_size,
                              hipStream_t stream) {
    const float* x_in = (const float*)d_in[0];
    const int* e_src = (const int*)d_in[1];
    const int* e_dst = (const int*)d_in[2];
    const float* w_l = (const float*)d_in[3];
    const float* b_l = (const float*)d_in[4];
    const float* w_r = (const float*)d_in[5];
    const float* gam = (const float*)d_in[6];
    const float* bet = (const float*)d_in[7];
    const float* w_res = (const float*)d_in[8];
    const float* b_res = (const float*)d_in[9];
    const float* w_fc = (const float*)d_in[10];
    const float* b_fc = (const float*)d_in[11];
    float* out = (float*)d_out;

    const int N = in_sizes[0] / D;
    const int E = in_sizes[1];
    const int nbuck = ((N - 1) >> BSHIFT) + 1;   // 196 for N=100000 (<= 512)
    const int eper = (E + CHUNKS - 1) / CHUNKS;

    size_t o = 0;
    auto carve = [&](size_t bytes) {
        size_t cur = o;
        o += (bytes + 255) & ~(size_t)255;
        return (char*)d_ws + cur;
    };
    int* row_ptr = (int*)carve((size_t)(N + 1) * 4);
    float* inv_deg = (float*)carve((size_t)N * 4);
    int* colA = (int*)carve((size_t)E * 4);
    int* staging = (int*)carve((size_t)nbuck * CAPB * 4);
    int* gcnt = (int*)carve((size_t)nbuck * 4);
    u16* WtL = (u16*)carve(3 * 64 * 128 * 2);
    u16* WresT = (u16*)carve(64 * 64 * 2);
    u16* WfcT = (u16*)carve(64 * 64 * 2);
    u16* xbA = (u16*)carve((size_t)N * D * 2);
    u16* xbB = (u16*)carve((size_t)N * D * 2);

    // CSR build: binAB (hist + bulk-reserve + scatter, tails folded) -> binC (sort)
    hipMemsetAsync(gcnt, 0, (size_t)nbuck * 4, stream);
    binAB_kernel<<<CHUNKS, 512, 0, stream>>>(e_src, e_dst, E, gcnt, staging,
                                             x_in, xbA, N * D / 4,
                                             w_l, w_r, w_res, w_fc, WtL, WresT, WfcT,
                                             nbuck, eper);
    binC_kernel<<<nbuck, 1024, 0, stream>>>(staging, gcnt, row_ptr, inv_deg, colA,
                                            N, nbuck);

    int gridT = (N + 63) / 64;

    // layer 0: xbA -> xbB  (residual via w_res MFMA)
    layer_kernel<<<gridT, 256, 0, stream>>>(xbA, row_ptr, colA, inv_deg, WtL,
                                            b_l, gam, bet, WresT, b_res,
                                            WfcT, b_fc, xbB, out, N, 1, 0);
    // layer 1: xbB -> xbA
    layer_kernel<<<gridT, 256, 0, stream>>>(xbB, row_ptr, colA, inv_deg, WtL + 8192,
                                            b_l + 64, gam + 64, bet + 64, WresT, b_res,
                                            WfcT, b_fc, xbA, out, N, 0, 0);
    // layer 2 + fused fc: xbA -> out (f32)
    layer_kernel<<<gridT, 256, 0, stream>>>(xbA, row_ptr, colA, inv_deg, WtL + 16384,
                                            b_l + 128, gam + 128, bet + 128, WresT, b_res,
                                            WfcT, b_fc, xbB, out, N, 0, 1);
}

// Round 11
// 274.168 us; speedup vs baseline: 1.0309x; 1.0309x over previous
//
#include <hip/hip_runtime.h>

typedef unsigned short u16;
typedef __bf16 bf16x8 __attribute__((ext_vector_type(8)));
typedef float f32x4 __attribute__((ext_vector_type(4)));

#define D 64
#define LPITCH 136   // 128 + 8 bf16 pad
#define CHUNKS 1024  // edge-array partitions (4 blocks/CU, 512 thr each)
#define BSHIFT 9     // 512 nodes per bucket (nbuck = 196 for N = 100000; max 512)
#define CAPB 10240   // padded per-bucket staging capacity (mean 8163, +23 sigma)
#define CCAP 1280    // LDS edge-list capacity per 64-node tile (mean ~1024, +2 sigma)

__device__ __forceinline__ float b2f(u16 u) {
    unsigned v = ((unsigned)u) << 16;
    float f;
    __builtin_memcpy(&f, &v, 4);
    return f;
}
__device__ __forceinline__ float u2f_lo(unsigned u) {
    unsigned v = u << 16;
    float f;
    __builtin_memcpy(&f, &v, 4);
    return f;
}
__device__ __forceinline__ float u2f_hi(unsigned u) {
    unsigned v = u & 0xFFFF0000u;
    float f;
    __builtin_memcpy(&f, &v, 4);
    return f;
}
__device__ __forceinline__ u16 f2b(float f) {
    unsigned u;
    __builtin_memcpy(&u, &f, 4);
    u = u + 0x7FFFu + ((u >> 16) & 1u);   // RNE
    return (u16)(u >> 16);
}
__device__ __forceinline__ bf16x8 ld_frag(const u16* p) {
    union { uint4 u; bf16x8 b; } cv;
    cv.u = *(const uint4*)p;
    return cv.b;
}

// ---------------- binAB: hist -> bulk-reserve (1 atomic per block,bucket) -> scatter
// Staging is PADDED: bucket b owns [b*CAPB, (b+1)*CAPB). Within-bucket order =
// arrival order (valid: segment-sum order unspecified). cvt/weight tails folded in.
__global__ __launch_bounds__(512) void binAB_kernel(
    const int* __restrict__ src, const int* __restrict__ dst, int E,
    int* __restrict__ gcnt,          // [nbuck], zeroed before launch
    int* __restrict__ staging,       // [nbuck*CAPB]
    const float* __restrict__ xf, u16* __restrict__ xb, int total4,
    const float* __restrict__ wl, const float* __restrict__ wr,
    const float* __restrict__ wres, const float* __restrict__ wfc,
    u16* __restrict__ WtL, u16* __restrict__ WresT, u16* __restrict__ WfcT,
    int nbuck, int eper) {
    __shared__ int hist[512];
    __shared__ int cur[512];
    int t = threadIdx.x;
    int c = blockIdx.x;
    int gid = c * 512 + t;
    int gstr = CHUNKS * 512;
    int beg = c * eper, end = min(beg + eper, E);

    hist[t] = 0;
    __syncthreads();
    // pass 1: chunk histogram (dst chunk ~6KB -> stays L1-hot for pass 2)
    for (int i = beg + t; i < end; i += 512)
        atomicAdd(&hist[dst[i] >> BSHIFT], 1);

    // tails (independent of hist; consumed by later dispatches)
    for (int i = gid; i < total4; i += gstr) {
        float4 v = *(const float4*)(xf + i * 4);
        ushort4 o;
        o.x = f2b(v.x); o.y = f2b(v.y); o.z = f2b(v.z); o.w = f2b(v.w);
        *(ushort4*)(xb + i * 4) = o;
    }
    for (int idx = gid; idx < 3 * 64 * 128; idx += gstr) {
        int l = idx >> 13;
        int rem = idx & 8191;
        int n = rem >> 7;
        int k = rem & 127;
        float v = (k < 64) ? wl[l * 4096 + k * 64 + n] : wr[l * 4096 + (k - 64) * 64 + n];
        WtL[idx] = f2b(v);
    }
    for (int idx = gid; idx < 4096; idx += gstr) {
        int n = idx >> 6, k = idx & 63;
        WresT[idx] = f2b(wres[k * 64 + n]);
        WfcT[idx] = f2b(wfc[k * 64 + n]);
    }
    __syncthreads();

    // bulk reservation: one global atomic per non-empty (block,bucket)
    for (int b = t; b < nbuck; b += 512) {
        int cnt = hist[b];
        int base = 0;
        if (cnt > 0) base = atomicAdd(&gcnt[b], cnt);
        cur[b] = b * CAPB + base;
    }
    __syncthreads();

    // pass 2: scatter packed (src | dlow<<17) into reserved cells
    const int mask = (1 << BSHIFT) - 1;
    for (int i = beg + t; i < end; i += 512) {
        int d = dst[i];
        int b = d >> BSHIFT;
        int p = atomicAdd(&cur[b], 1);
        if (p < (b + 1) * CAPB)                // overflow guard (prob ~0)
            staging[p] = src[i] | ((d & mask) << 17);
    }
}

// ---------------- binC: per-bucket degree hist + scan + col scatter (LDS only) ------
// 1024 threads/block (16 waves/CU): the two 8K LDS-atomic passes need concurrency.
__global__ __launch_bounds__(1024) void binC_kernel(const int* __restrict__ staging,
                                                    const int* __restrict__ T,
                                                    int* __restrict__ row_ptr,
                                                    float* __restrict__ inv_deg,
                                                    int* __restrict__ col, int N, int nbuck) {
    __shared__ int cnt[512];
    __shared__ int lrp[512];
    __shared__ int sm[512];
    __shared__ int span[2];
    int b = blockIdx.x;
    int t = threadIdx.x;
    // compact bucket base via scan of clamped T over 512 slots (threads t<512)
    int h = 0;
    if (t < 512) {
        h = (t < nbuck) ? min(T[t], CAPB) : 0;
        sm[t] = h;
    }
    __syncthreads();
    for (int off = 1; off < 512; off <<= 1) {
        int v = (t < 512 && t >= off) ? sm[t - off] : 0;
        __syncthreads();
        if (t < 512) sm[t] += v;
        __syncthreads();
    }
    if (t == b) { span[0] = sm[t] - h; span[1] = sm[t]; }   // b < nbuck <= 512
    if (b == 0 && t == 511) row_ptr[N] = sm[511];           // compact total (== E)
    if (t < 512) cnt[t] = 0;
    __syncthreads();
    int sbeg = span[0];
    int scount = span[1] - span[0];
    int pbeg = b * CAPB;
    int node0 = b << BSHIFT;
    int nn = min(1 << BSHIFT, N - node0);
    for (int i = t; i < scount; i += 1024)
        atomicAdd(&cnt[staging[pbeg + i] >> 17], 1);
    __syncthreads();
    int c0 = 0;
    if (t < 512) {
        c0 = cnt[t];
        sm[t] = c0;
    }
    __syncthreads();
    for (int off = 1; off < 512; off <<= 1) {
        int v = (t < 512 && t >= off) ? sm[t - off] : 0;
        __syncthreads();
        if (t < 512) sm[t] += v;
        __syncthreads();
    }
    if (t < 512) lrp[t] = sm[t] - c0;   // exclusive
    __syncthreads();
    if (t < nn) {
        row_ptr[node0 + t] = sbeg + lrp[t];
        inv_deg[node0 + t] = c0 > 0 ? 1.0f / (float)c0 : 0.0f;
    }
    __syncthreads();
    for (int i = t; i < scount; i += 1024) {
        int word = staging[pbeg + i];
        int ld = word >> 17;
        int k = atomicSub(&cnt[ld], 1) - 1;
        col[sbeg + lrp[ld] + k] = word & 0x1FFFF;
    }
}

// ---------------- fused SAGE layer: gather-mean + GEMM + LN + ReLU + residual --------
// R7-proven structure (sB + sA LDS staging; R9 lesson: register-x/global-residual
// variants ADD HBM traffic and lose). Single change vs R7: gather main loop widened
// 8 -> 16 edges/iter (16 outstanding loads/lane) to halve latency exposures.
// NOTE (R3 lesson): LDS f32-atomic aggregation is ~13x slower; register
// slot-accumulation + per-node-sorted col is the fast structure.
__global__ __launch_bounds__(256, 4) void layer_kernel(const u16* __restrict__ xb_in,
                                                       const int* __restrict__ row_ptr,
                                                       const int* __restrict__ col,
                                                       const float* __restrict__ inv_deg,
                                                       const u16* __restrict__ Wt,    // [64][128]
                                                       const float* __restrict__ bl,
                                                       const float* __restrict__ gam,
                                                       const float* __restrict__ bet,
                                                       const u16* __restrict__ WresT, // [64][64]
                                                       const float* __restrict__ bres,
                                                       const u16* __restrict__ WfcT,  // [64][64]
                                                       const float* __restrict__ bfc,
                                                       u16* __restrict__ xb_out,
                                                       float* __restrict__ fout,
                                                       int N, int layer0, int final_) {
    __shared__ __align__(16) u16 sA[64 * LPITCH];
    __shared__ __align__(16) u16 sB[64 * LPITCH];   // weights; reused as f32 stage in final
    __shared__ int lcol[CCAP];
    __shared__ int rp[65];
    __shared__ float ideg[64];
    int tid = threadIdx.x;
    int base = blockIdx.x * 64;
    int lane = tid & 63;
    int w = tid >> 6;

    // stage B (W^T rows), 4 uint4 per thread
#pragma unroll
    for (int i = 0; i < 4; i++) {
        int idx = i * 256 + tid;
        int r = idx >> 4, c = idx & 15;
        *(uint4*)&sB[r * LPITCH + c * 8] = *(const uint4*)(Wt + idx * 8);
    }
    // stage x rows into sA cols 64..127, 2 uint4 per thread
#pragma unroll
    for (int i = 0; i < 2; i++) {
        int idx = i * 256 + tid;
        int r = idx >> 3, c = idx & 7;
        int node = base + r;
        uint4 v = make_uint4(0, 0, 0, 0);
        if (node < N) v = *(const uint4*)(xb_in + node * D + c * 8);
        *(uint4*)&sA[r * LPITCH + 64 + c * 8] = v;
    }
    if (tid < 65) rp[tid] = row_ptr[min(base + tid, N)];
    if (tid < 64) ideg[tid] = (base + tid < N) ? inv_deg[base + tid] : 0.f;
    __syncthreads();

    int e0 = rp[0];
    int tileE = rp[64] - e0;
    bool fits = tileE <= CCAP;
    if (fits) {
        for (int i = tid; i < tileE; i += 256) lcol[i] = col[e0 + i];
    }
    __syncthreads();

    // gather stage: slot-per-node, 2 rounds x 8 slots per wave = 16 nodes/wave
    int slot = lane >> 3;
    int chunk = lane & 7;
    auto run_gather = [&](auto LD) {
#pragma unroll
        for (int r = 0; r < 2; r++) {
            int node_l = w * 16 + r * 8 + slot;
            float a0 = 0, a1 = 0, a2 = 0, a3 = 0, a4 = 0, a5 = 0, a6 = 0, a7 = 0;
            int e = rp[node_l], end = rp[node_l + 1];
#define ACC(v)                                          \
    a0 += u2f_lo(v.x); a1 += u2f_hi(v.x);               \
    a2 += u2f_lo(v.y); a3 += u2f_hi(v.y);               \
    a4 += u2f_lo(v.z); a5 += u2f_hi(v.z);               \
    a6 += u2f_lo(v.w); a7 += u2f_hi(v.w);
            // main loop: 16 edges/iter, 16 outstanding loads (fully unrolled,
            // static indices -> registers, not scratch)
            for (; e + 15 < end; e += 16) {
                int ss[16];
#pragma unroll
                for (int j = 0; j < 16; j++) ss[j] = LD(e + j);
                uint4 vv[16];
#pragma unroll
                for (int j = 0; j < 16; j++)
                    vv[j] = *(const uint4*)(xb_in + ss[j] * D + chunk * 8);
#pragma unroll
                for (int j = 0; j < 16; j++) { ACC(vv[j]) }
            }
            if (e + 7 < end) {
                int s0 = LD(e),     s1 = LD(e + 1), s2 = LD(e + 2), s3 = LD(e + 3);
                int s4 = LD(e + 4), s5 = LD(e + 5), s6 = LD(e + 6), s7 = LD(e + 7);
                uint4 v0 = *(const uint4*)(xb_in + s0 * D + chunk * 8);
                uint4 v1 = *(const uint4*)(xb_in + s1 * D + chunk * 8);
                uint4 v2 = *(const uint4*)(xb_in + s2 * D + chunk * 8);
                uint4 v3 = *(const uint4*)(xb_in + s3 * D + chunk * 8);
                uint4 v4 = *(const uint4*)(xb_in + s4 * D + chunk * 8);
                uint4 v5 = *(const uint4*)(xb_in + s5 * D + chunk * 8);
                uint4 v6 = *(const uint4*)(xb_in + s6 * D + chunk * 8);
                uint4 v7 = *(const uint4*)(xb_in + s7 * D + chunk * 8);
                ACC(v0) ACC(v1) ACC(v2) ACC(v3)
                ACC(v4) ACC(v5) ACC(v6) ACC(v7)
                e += 8;
            }
            if (e + 3 < end) {
                int s0 = LD(e), s1 = LD(e + 1), s2 = LD(e + 2), s3 = LD(e + 3);
                uint4 v0 = *(const uint4*)(xb_in + s0 * D + chunk * 8);
                uint4 v1 = *(const uint4*)(xb_in + s1 * D + chunk * 8);
                uint4 v2 = *(const uint4*)(xb_in + s2 * D + chunk * 8);
                uint4 v3 = *(const uint4*)(xb_in + s3 * D + chunk * 8);
                ACC(v0) ACC(v1) ACC(v2) ACC(v3)
                e += 4;
            }
            if (e + 1 < end) {
                int s0 = LD(e), s1 = LD(e + 1);
                uint4 v0 = *(const uint4*)(xb_in + s0 * D + chunk * 8);
                uint4 v1 = *(const uint4*)(xb_in + s1 * D + chunk * 8);
                ACC(v0) ACC(v1)
                e += 2;
            }
            if (e < end) {
                int s0 = LD(e);
                uint4 v0 = *(const uint4*)(xb_in + s0 * D + chunk * 8);
                ACC(v0)
            }
#undef ACC
            float m = ideg[node_l];
            uint4 o;
            o.x = (unsigned)f2b(a0 * m) | ((unsigned)f2b(a1 * m) << 16);
            o.y = (unsigned)f2b(a2 * m) | ((unsigned)f2b(a3 * m) << 16);
            o.z = (unsigned)f2b(a4 * m) | ((unsigned)f2b(a5 * m) << 16);
            o.w = (unsigned)f2b(a6 * m) | ((unsigned)f2b(a7 * m) << 16);
            *(uint4*)&sA[node_l * LPITCH + chunk * 8] = o;
        }
    };
    if (fits) run_gather([&](int e) { return lcol[e - e0]; });
    else      run_gather([&](int e) { return col[e]; });
    __syncthreads();

    // GEMM stage
    int q = lane >> 4;
    int ln = lane & 15;
    f32x4 acc[4] = {{0, 0, 0, 0}, {0, 0, 0, 0}, {0, 0, 0, 0}, {0, 0, 0, 0}};
    f32x4 accr[4] = {{0, 0, 0, 0}, {0, 0, 0, 0}, {0, 0, 0, 0}, {0, 0, 0, 0}};
    const u16* aRow = &sA[(w * 16 + ln) * LPITCH];

#pragma unroll
    for (int c = 0; c < 4; c++) {       // K = 128
        bf16x8 a = ld_frag(&aRow[c * 32 + q * 8]);
#pragma unroll
        for (int t = 0; t < 4; t++) {
            bf16x8 b = ld_frag(&sB[(t * 16 + ln) * LPITCH + c * 32 + q * 8]);
            acc[t] = __builtin_amdgcn_mfma_f32_16x16x32_bf16(a, b, acc[t], 0, 0, 0);
        }
    }
    if (layer0) {                       // residual = x @ w_res (one-shot global loads)
#pragma unroll
        for (int c = 0; c < 2; c++) {
            bf16x8 a = ld_frag(&aRow[64 + c * 32 + q * 8]);
#pragma unroll
            for (int t = 0; t < 4; t++) {
                bf16x8 b = ld_frag(WresT + (t * 16 + ln) * 64 + c * 32 + q * 8);
                accr[t] = __builtin_amdgcn_mfma_f32_16x16x32_bf16(a, b, accr[t], 0, 0, 0);
            }
        }
    }

    float bcol[4], gcol[4], btcol[4], brcol[4];
#pragma unroll
    for (int t = 0; t < 4; t++) {
        int colI = t * 16 + ln;
        bcol[t] = bl[colI];
        gcol[t] = gam[colI];
        btcol[t] = bet[colI];
        brcol[t] = layer0 ? bres[colI] : 0.f;
    }
#pragma unroll
    for (int t = 0; t < 4; t++)
#pragma unroll
        for (int r = 0; r < 4; r++) acc[t][r] += bcol[t];

    float ps[4], pq[4];
#pragma unroll
    for (int r = 0; r < 4; r++) {
        float s = 0, s2 = 0;
#pragma unroll
        for (int t = 0; t < 4; t++) { float h = acc[t][r]; s += h; s2 += h * h; }
        ps[r] = s; pq[r] = s2;
    }
    for (int off = 1; off < 16; off <<= 1) {
#pragma unroll
        for (int r = 0; r < 4; r++) {
            ps[r] += __shfl_xor(ps[r], off, 64);
            pq[r] += __shfl_xor(pq[r], off, 64);
        }
    }
    // epilogue -> sA cols 0..63 (wave-local rows; in-wave LDS dep, no barrier)
#pragma unroll
    for (int r = 0; r < 4; r++) {
        int nb = w * 16 + q * 4 + r;
        float mu = ps[r] * (1.f / 64.f);
        float var = pq[r] * (1.f / 64.f) - mu * mu;
        var = var < 0.f ? 0.f : var;
        float rstd = rsqrtf(var + 1e-5f);
#pragma unroll
        for (int t = 0; t < 4; t++) {
            int colI = t * 16 + ln;
            float hn = (acc[t][r] - mu) * rstd * gcol[t] + btcol[t];
            hn = hn > 0.f ? hn : 0.f;
            float res = layer0 ? (accr[t][r] + brcol[t])
                               : b2f(sA[nb * LPITCH + 64 + colI]);
            sA[nb * LPITCH + colI] = f2b(hn + res);
        }
    }

    if (final_) {
        // FC: out = x3 @ w_fc + b_fc; stage f32 through sB (dead after GEMM) for
        // coalesced float4 writeback. Pitch 68 floats breaks bank aliasing.
        f32x4 accf[4] = {{0, 0, 0, 0}, {0, 0, 0, 0}, {0, 0, 0, 0}, {0, 0, 0, 0}};
#pragma unroll
        for (int c = 0; c < 2; c++) {
            bf16x8 a = ld_frag(&aRow[c * 32 + q * 8]);
#pragma unroll
            for (int t = 0; t < 4; t++) {
                bf16x8 b = ld_frag(WfcT + (t * 16 + ln) * 64 + c * 32 + q * 8);
                accf[t] = __builtin_amdgcn_mfma_f32_16x16x32_bf16(a, b, accf[t], 0, 0, 0);
            }
        }
        __syncthreads();               // all waves done reading sB
        float* fB = (float*)sB;        // 64 rows x pitch 68 = 4352 floats = 17408 B
#pragma unroll
        for (int r = 0; r < 4; r++) {
            int nb = w * 16 + q * 4 + r;
#pragma unroll
            for (int t = 0; t < 4; t++) {
                int colI = t * 16 + ln;
                fB[nb * 68 + colI] = accf[t][r] + bfc[colI];
            }
        }
        __syncthreads();
#pragma unroll
        for (int i = 0; i < 4; i++) {
            int idx = i * 256 + tid;
            int row = idx >> 4, cc = idx & 15;
            int node = base + row;
            if (node < N)
                *(float4*)(fout + node * D + cc * 4) = *(const float4*)&fB[row * 68 + cc * 4];
        }
    } else {
        // coalesced writeback of this wave's 16 rows (2 uint4 per thread)
#pragma unroll
        for (int i = 0; i < 2; i++) {
            int idx = i * 64 + lane;
            int row = w * 16 + (idx >> 3);
            int ch = idx & 7;
            int node = base + row;
            if (node < N)
                *(uint4*)(xb_out + node * D + ch * 8) = *(const uint4*)&sA[row * LPITCH + ch * 8];
        }
    }
}

extern "C" void kernel_launch(void* const* d_in, const int* in_sizes, int n_in,
                              void* d_out, int out_size, void* d_ws, size_t ws_size,
                              hipStream_t stream) {
    const float* x_in = (const float*)d_in[0];
    const int* e_src = (const int*)d_in[1];
    const int* e_dst = (const int*)d_in[2];
    const float* w_l = (const float*)d_in[3];
    const float* b_l = (const float*)d_in[4];
    const float* w_r = (const float*)d_in[5];
    const float* gam = (const float*)d_in[6];
    const float* bet = (const float*)d_in[7];
    const float* w_res = (const float*)d_in[8];
    const float* b_res = (const float*)d_in[9];
    const float* w_fc = (const float*)d_in[10];
    const float* b_fc = (const float*)d_in[11];
    float* out = (float*)d_out;

    const int N = in_sizes[0] / D;
    const int E = in_sizes[1];
    const int nbuck = ((N - 1) >> BSHIFT) + 1;   // 196 for N=100000 (<= 512)
    const int eper = (E + CHUNKS - 1) / CHUNKS;

    size_t o = 0;
    auto carve = [&](size_t bytes) {
        size_t cur = o;
        o += (bytes + 255) & ~(size_t)255;
        return (char*)d_ws + cur;
    };
    int* row_ptr = (int*)carve((size_t)(N + 1) * 4);
    float* inv_deg = (float*)carve((size_t)N * 4);
    int* colA = (int*)carve((size_t)E * 4);
    int* staging = (int*)carve((size_t)nbuck * CAPB * 4);
    int* gcnt = (int*)carve((size_t)nbuck * 4);
    u16* WtL = (u16*)carve(3 * 64 * 128 * 2);
    u16* WresT = (u16*)carve(64 * 64 * 2);
    u16* WfcT = (u16*)carve(64 * 64 * 2);
    u16* xbA = (u16*)carve((size_t)N * D * 2);
    u16* xbB = (u16*)carve((size_t)N * D * 2);

    // CSR build: binAB (hist + bulk-reserve + scatter, tails folded) -> binC (sort)
    hipMemsetAsync(gcnt, 0, (size_t)nbuck * 4, stream);
    binAB_kernel<<<CHUNKS, 512, 0, stream>>>(e_src, e_dst, E, gcnt, staging,
                                             x_in, xbA, N * D / 4,
                                             w_l, w_r, w_res, w_fc, WtL, WresT, WfcT,
                                             nbuck, eper);
    binC_kernel<<<nbuck, 1024, 0, stream>>>(staging, gcnt, row_ptr, inv_deg, colA,
                                            N, nbuck);

    int gridT = (N + 63) / 64;

    // layer 0: xbA -> xbB  (residual via w_res MFMA)
    layer_kernel<<<gridT, 256, 0, stream>>>(xbA, row_ptr, colA, inv_deg, WtL,
                                            b_l, gam, bet, WresT, b_res,
                                            WfcT, b_fc, xbB, out, N, 1, 0);
    // layer 1: xbB -> xbA
    layer_kernel<<<gridT, 256, 0, stream>>>(xbB, row_ptr, colA, inv_deg, WtL + 8192,
                                            b_l + 64, gam + 64, bet + 64, WresT, b_res,
                                            WfcT, b_fc, xbA, out, N, 0, 0);
    // layer 2 + fused fc: xbA -> out (f32)
    layer_kernel<<<gridT, 256, 0, stream>>>(xbA, row_ptr, colA, inv_deg, WtL + 16384,
                                            b_l + 128, gam + 128, bet + 128, WresT, b_res,
                                            WfcT, b_fc, xbB, out, N, 0, 1);
}

// Round 12
// 259.955 us; speedup vs baseline: 1.0873x; 1.0547x over previous
//
#include <hip/hip_runtime.h>

typedef unsigned short u16;
typedef __bf16 bf16x8 __attribute__((ext_vector_type(8)));
typedef float f32x4 __attribute__((ext_vector_type(4)));

#define D 64
#define LPITCH 136   // 128 + 8 bf16 pad
#define CHUNKS 1024  // edge-array partitions (4 blocks/CU, 512 thr each)
#define BSHIFT 9     // 512 nodes per bucket (nbuck = 196 for N = 100000; max 512)
#define CAPB 10240   // padded per-bucket staging capacity (mean 8163, +23 sigma)
#define CCAP 1280    // LDS edge-list capacity per 64-node tile (mean ~1024, +2 sigma)

__device__ __forceinline__ float b2f(u16 u) {
    unsigned v = ((unsigned)u) << 16;
    float f;
    __builtin_memcpy(&f, &v, 4);
    return f;
}
__device__ __forceinline__ float u2f_lo(unsigned u) {
    unsigned v = u << 16;
    float f;
    __builtin_memcpy(&f, &v, 4);
    return f;
}
__device__ __forceinline__ float u2f_hi(unsigned u) {
    unsigned v = u & 0xFFFF0000u;
    float f;
    __builtin_memcpy(&f, &v, 4);
    return f;
}
__device__ __forceinline__ u16 f2b(float f) {
    unsigned u;
    __builtin_memcpy(&u, &f, 4);
    u = u + 0x7FFFu + ((u >> 16) & 1u);   // RNE
    return (u16)(u >> 16);
}
__device__ __forceinline__ bf16x8 ld_frag(const u16* p) {
    union { uint4 u; bf16x8 b; } cv;
    cv.u = *(const uint4*)p;
    return cv.b;
}

// ---------------- binAB: hist -> bulk-reserve (1 atomic per block,bucket) -> scatter
// Staging is PADDED: bucket b owns [b*CAPB, (b+1)*CAPB). Within-bucket order =
// arrival order (valid: segment-sum order unspecified). cvt/weight tails folded in.
__global__ __launch_bounds__(512) void binAB_kernel(
    const int* __restrict__ src, const int* __restrict__ dst, int E,
    int* __restrict__ gcnt,          // [nbuck], zeroed before launch
    int* __restrict__ staging,       // [nbuck*CAPB]
    const float* __restrict__ xf, u16* __restrict__ xb, int total4,
    const float* __restrict__ wl, const float* __restrict__ wr,
    const float* __restrict__ wres, const float* __restrict__ wfc,
    u16* __restrict__ WtL, u16* __restrict__ WresT, u16* __restrict__ WfcT,
    int nbuck, int eper) {
    __shared__ int hist[512];
    __shared__ int cur[512];
    int t = threadIdx.x;
    int c = blockIdx.x;
    int gid = c * 512 + t;
    int gstr = CHUNKS * 512;
    int beg = c * eper, end = min(beg + eper, E);

    hist[t] = 0;
    __syncthreads();
    // pass 1: chunk histogram (dst chunk ~6KB -> stays L1-hot for pass 2)
    for (int i = beg + t; i < end; i += 512)
        atomicAdd(&hist[dst[i] >> BSHIFT], 1);

    // tails (independent of hist; consumed by later dispatches)
    for (int i = gid; i < total4; i += gstr) {
        float4 v = *(const float4*)(xf + i * 4);
        ushort4 o;
        o.x = f2b(v.x); o.y = f2b(v.y); o.z = f2b(v.z); o.w = f2b(v.w);
        *(ushort4*)(xb + i * 4) = o;
    }
    for (int idx = gid; idx < 3 * 64 * 128; idx += gstr) {
        int l = idx >> 13;
        int rem = idx & 8191;
        int n = rem >> 7;
        int k = rem & 127;
        float v = (k < 64) ? wl[l * 4096 + k * 64 + n] : wr[l * 4096 + (k - 64) * 64 + n];
        WtL[idx] = f2b(v);
    }
    for (int idx = gid; idx < 4096; idx += gstr) {
        int n = idx >> 6, k = idx & 63;
        WresT[idx] = f2b(wres[k * 64 + n]);
        WfcT[idx] = f2b(wfc[k * 64 + n]);
    }
    __syncthreads();

    // bulk reservation: one global atomic per non-empty (block,bucket)
    for (int b = t; b < nbuck; b += 512) {
        int cnt = hist[b];
        int base = 0;
        if (cnt > 0) base = atomicAdd(&gcnt[b], cnt);
        cur[b] = b * CAPB + base;
    }
    __syncthreads();

    // pass 2: scatter packed (src | dlow<<17) into reserved cells
    const int mask = (1 << BSHIFT) - 1;
    for (int i = beg + t; i < end; i += 512) {
        int d = dst[i];
        int b = d >> BSHIFT;
        int p = atomicAdd(&cur[b], 1);
        if (p < (b + 1) * CAPB)                // overflow guard (prob ~0)
            staging[p] = src[i] | ((d & mask) << 17);
    }
}

// ---------------- binC: per-bucket degree hist + scan + col scatter (LDS only) ------
// 1024 threads/block (16 waves/CU): the two 8K LDS-atomic passes need concurrency.
__global__ __launch_bounds__(1024) void binC_kernel(const int* __restrict__ staging,
                                                    const int* __restrict__ T,
                                                    int* __restrict__ row_ptr,
                                                    float* __restrict__ inv_deg,
                                                    int* __restrict__ col, int N, int nbuck) {
    __shared__ int cnt[512];
    __shared__ int lrp[512];
    __shared__ int sm[512];
    __shared__ int span[2];
    int b = blockIdx.x;
    int t = threadIdx.x;
    // compact bucket base via scan of clamped T over 512 slots (threads t<512)
    int h = 0;
    if (t < 512) {
        h = (t < nbuck) ? min(T[t], CAPB) : 0;
        sm[t] = h;
    }
    __syncthreads();
    for (int off = 1; off < 512; off <<= 1) {
        int v = (t < 512 && t >= off) ? sm[t - off] : 0;
        __syncthreads();
        if (t < 512) sm[t] += v;
        __syncthreads();
    }
    if (t == b) { span[0] = sm[t] - h; span[1] = sm[t]; }   // b < nbuck <= 512
    if (b == 0 && t == 511) row_ptr[N] = sm[511];           // compact total (== E)
    if (t < 512) cnt[t] = 0;
    __syncthreads();
    int sbeg = span[0];
    int scount = span[1] - span[0];
    int pbeg = b * CAPB;
    int node0 = b << BSHIFT;
    int nn = min(1 << BSHIFT, N - node0);
    for (int i = t; i < scount; i += 1024)
        atomicAdd(&cnt[staging[pbeg + i] >> 17], 1);
    __syncthreads();
    int c0 = 0;
    if (t < 512) {
        c0 = cnt[t];
        sm[t] = c0;
    }
    __syncthreads();
    for (int off = 1; off < 512; off <<= 1) {
        int v = (t < 512 && t >= off) ? sm[t - off] : 0;
        __syncthreads();
        if (t < 512) sm[t] += v;
        __syncthreads();
    }
    if (t < 512) lrp[t] = sm[t] - c0;   // exclusive
    __syncthreads();
    if (t < nn) {
        row_ptr[node0 + t] = sbeg + lrp[t];
        inv_deg[node0 + t] = c0 > 0 ? 1.0f / (float)c0 : 0.0f;
    }
    __syncthreads();
    for (int i = t; i < scount; i += 1024) {
        int word = staging[pbeg + i];
        int ld = word >> 17;
        int k = atomicSub(&cnt[ld], 1) - 1;
        col[sbeg + lrp[ld] + k] = word & 0x1FFFF;
    }
}

// ---------------- fused SAGE layer: gather-mean + GEMM + LN + ReLU + residual --------
// R7-proven config (best measured: 265.2us total, 45.7us/layer).
// Lessons locked in: sB+sA LDS staging required (R6/R9: global-B or global-residual
// variants add HBM traffic and lose); gather load window is compiler-capped at ~8
// (R11: 16-wide unroll re-serialized, VGPR stayed 52, +6% time); LDS f32-atomic
// aggregation ~13x slower than register slot-accumulation (R3).
__global__ __launch_bounds__(256, 4) void layer_kernel(const u16* __restrict__ xb_in,
                                                       const int* __restrict__ row_ptr,
                                                       const int* __restrict__ col,
                                                       const float* __restrict__ inv_deg,
                                                       const u16* __restrict__ Wt,    // [64][128]
                                                       const float* __restrict__ bl,
                                                       const float* __restrict__ gam,
                                                       const float* __restrict__ bet,
                                                       const u16* __restrict__ WresT, // [64][64]
                                                       const float* __restrict__ bres,
                                                       const u16* __restrict__ WfcT,  // [64][64]
                                                       const float* __restrict__ bfc,
                                                       u16* __restrict__ xb_out,
                                                       float* __restrict__ fout,
                                                       int N, int layer0, int final_) {
    __shared__ __align__(16) u16 sA[64 * LPITCH];
    __shared__ __align__(16) u16 sB[64 * LPITCH];   // weights; reused as f32 stage in final
    __shared__ int lcol[CCAP];
    __shared__ int rp[65];
    __shared__ float ideg[64];
    int tid = threadIdx.x;
    int base = blockIdx.x * 64;
    int lane = tid & 63;
    int w = tid >> 6;

    // stage B (W^T rows), 4 uint4 per thread
#pragma unroll
    for (int i = 0; i < 4; i++) {
        int idx = i * 256 + tid;
        int r = idx >> 4, c = idx & 15;
        *(uint4*)&sB[r * LPITCH + c * 8] = *(const uint4*)(Wt + idx * 8);
    }
    // stage x rows into sA cols 64..127, 2 uint4 per thread
#pragma unroll
    for (int i = 0; i < 2; i++) {
        int idx = i * 256 + tid;
        int r = idx >> 3, c = idx & 7;
        int node = base + r;
        uint4 v = make_uint4(0, 0, 0, 0);
        if (node < N) v = *(const uint4*)(xb_in + node * D + c * 8);
        *(uint4*)&sA[r * LPITCH + 64 + c * 8] = v;
    }
    if (tid < 65) rp[tid] = row_ptr[min(base + tid, N)];
    if (tid < 64) ideg[tid] = (base + tid < N) ? inv_deg[base + tid] : 0.f;
    __syncthreads();

    int e0 = rp[0];
    int tileE = rp[64] - e0;
    bool fits = tileE <= CCAP;
    if (fits) {
        for (int i = tid; i < tileE; i += 256) lcol[i] = col[e0 + i];
    }
    __syncthreads();

    // gather stage: slot-per-node, 2 rounds x 8 slots per wave = 16 nodes/wave
    int slot = lane >> 3;
    int chunk = lane & 7;
    auto run_gather = [&](auto LD) {
#pragma unroll
        for (int r = 0; r < 2; r++) {
            int node_l = w * 16 + r * 8 + slot;
            float a0 = 0, a1 = 0, a2 = 0, a3 = 0, a4 = 0, a5 = 0, a6 = 0, a7 = 0;
            int e = rp[node_l], end = rp[node_l + 1];
#define ACC(v)                                          \
    a0 += u2f_lo(v.x); a1 += u2f_hi(v.x);               \
    a2 += u2f_lo(v.y); a3 += u2f_hi(v.y);               \
    a4 += u2f_lo(v.z); a5 += u2f_hi(v.z);               \
    a6 += u2f_lo(v.w); a7 += u2f_hi(v.w);
            for (; e + 7 < end; e += 8) {
                int s0 = LD(e),     s1 = LD(e + 1), s2 = LD(e + 2), s3 = LD(e + 3);
                int s4 = LD(e + 4), s5 = LD(e + 5), s6 = LD(e + 6), s7 = LD(e + 7);
                uint4 v0 = *(const uint4*)(xb_in + s0 * D + chunk * 8);
                uint4 v1 = *(const uint4*)(xb_in + s1 * D + chunk * 8);
                uint4 v2 = *(const uint4*)(xb_in + s2 * D + chunk * 8);
                uint4 v3 = *(const uint4*)(xb_in + s3 * D + chunk * 8);
                uint4 v4 = *(const uint4*)(xb_in + s4 * D + chunk * 8);
                uint4 v5 = *(const uint4*)(xb_in + s5 * D + chunk * 8);
                uint4 v6 = *(const uint4*)(xb_in + s6 * D + chunk * 8);
                uint4 v7 = *(const uint4*)(xb_in + s7 * D + chunk * 8);
                ACC(v0) ACC(v1) ACC(v2) ACC(v3)
                ACC(v4) ACC(v5) ACC(v6) ACC(v7)
            }
            if (e + 3 < end) {
                int s0 = LD(e), s1 = LD(e + 1), s2 = LD(e + 2), s3 = LD(e + 3);
                uint4 v0 = *(const uint4*)(xb_in + s0 * D + chunk * 8);
                uint4 v1 = *(const uint4*)(xb_in + s1 * D + chunk * 8);
                uint4 v2 = *(const uint4*)(xb_in + s2 * D + chunk * 8);
                uint4 v3 = *(const uint4*)(xb_in + s3 * D + chunk * 8);
                ACC(v0) ACC(v1) ACC(v2) ACC(v3)
                e += 4;
            }
            if (e + 1 < end) {
                int s0 = LD(e), s1 = LD(e + 1);
                uint4 v0 = *(const uint4*)(xb_in + s0 * D + chunk * 8);
                uint4 v1 = *(const uint4*)(xb_in + s1 * D + chunk * 8);
                ACC(v0) ACC(v1)
                e += 2;
            }
            if (e < end) {
                int s0 = LD(e);
                uint4 v0 = *(const uint4*)(xb_in + s0 * D + chunk * 8);
                ACC(v0)
            }
#undef ACC
            float m = ideg[node_l];
            uint4 o;
            o.x = (unsigned)f2b(a0 * m) | ((unsigned)f2b(a1 * m) << 16);
            o.y = (unsigned)f2b(a2 * m) | ((unsigned)f2b(a3 * m) << 16);
            o.z = (unsigned)f2b(a4 * m) | ((unsigned)f2b(a5 * m) << 16);
            o.w = (unsigned)f2b(a6 * m) | ((unsigned)f2b(a7 * m) << 16);
            *(uint4*)&sA[node_l * LPITCH + chunk * 8] = o;
        }
    };
    if (fits) run_gather([&](int e) { return lcol[e - e0]; });
    else      run_gather([&](int e) { return col[e]; });
    __syncthreads();

    // GEMM stage
    int q = lane >> 4;
    int ln = lane & 15;
    f32x4 acc[4] = {{0, 0, 0, 0}, {0, 0, 0, 0}, {0, 0, 0, 0}, {0, 0, 0, 0}};
    f32x4 accr[4] = {{0, 0, 0, 0}, {0, 0, 0, 0}, {0, 0, 0, 0}, {0, 0, 0, 0}};
    const u16* aRow = &sA[(w * 16 + ln) * LPITCH];

#pragma unroll
    for (int c = 0; c < 4; c++) {       // K = 128
        bf16x8 a = ld_frag(&aRow[c * 32 + q * 8]);
#pragma unroll
        for (int t = 0; t < 4; t++) {
            bf16x8 b = ld_frag(&sB[(t * 16 + ln) * LPITCH + c * 32 + q * 8]);
            acc[t] = __builtin_amdgcn_mfma_f32_16x16x32_bf16(a, b, acc[t], 0, 0, 0);
        }
    }
    if (layer0) {                       // residual = x @ w_res (one-shot global loads)
#pragma unroll
        for (int c = 0; c < 2; c++) {
            bf16x8 a = ld_frag(&aRow[64 + c * 32 + q * 8]);
#pragma unroll
            for (int t = 0; t < 4; t++) {
                bf16x8 b = ld_frag(WresT + (t * 16 + ln) * 64 + c * 32 + q * 8);
                accr[t] = __builtin_amdgcn_mfma_f32_16x16x32_bf16(a, b, accr[t], 0, 0, 0);
            }
        }
    }

    float bcol[4], gcol[4], btcol[4], brcol[4];
#pragma unroll
    for (int t = 0; t < 4; t++) {
        int colI = t * 16 + ln;
        bcol[t] = bl[colI];
        gcol[t] = gam[colI];
        btcol[t] = bet[colI];
        brcol[t] = layer0 ? bres[colI] : 0.f;
    }
#pragma unroll
    for (int t = 0; t < 4; t++)
#pragma unroll
        for (int r = 0; r < 4; r++) acc[t][r] += bcol[t];

    float ps[4], pq[4];
#pragma unroll
    for (int r = 0; r < 4; r++) {
        float s = 0, s2 = 0;
#pragma unroll
        for (int t = 0; t < 4; t++) { float h = acc[t][r]; s += h; s2 += h * h; }
        ps[r] = s; pq[r] = s2;
    }
    for (int off = 1; off < 16; off <<= 1) {
#pragma unroll
        for (int r = 0; r < 4; r++) {
            ps[r] += __shfl_xor(ps[r], off, 64);
            pq[r] += __shfl_xor(pq[r], off, 64);
        }
    }
    // epilogue -> sA cols 0..63 (wave-local rows; in-wave LDS dep, no barrier)
#pragma unroll
    for (int r = 0; r < 4; r++) {
        int nb = w * 16 + q * 4 + r;
        float mu = ps[r] * (1.f / 64.f);
        float var = pq[r] * (1.f / 64.f) - mu * mu;
        var = var < 0.f ? 0.f : var;
        float rstd = rsqrtf(var + 1e-5f);
#pragma unroll
        for (int t = 0; t < 4; t++) {
            int colI = t * 16 + ln;
            float hn = (acc[t][r] - mu) * rstd * gcol[t] + btcol[t];
            hn = hn > 0.f ? hn : 0.f;
            float res = layer0 ? (accr[t][r] + brcol[t])
                               : b2f(sA[nb * LPITCH + 64 + colI]);
            sA[nb * LPITCH + colI] = f2b(hn + res);
        }
    }

    if (final_) {
        // FC: out = x3 @ w_fc + b_fc; stage f32 through sB (dead after GEMM) for
        // coalesced float4 writeback. Pitch 68 floats breaks bank aliasing.
        f32x4 accf[4] = {{0, 0, 0, 0}, {0, 0, 0, 0}, {0, 0, 0, 0}, {0, 0, 0, 0}};
#pragma unroll
        for (int c = 0; c < 2; c++) {
            bf16x8 a = ld_frag(&aRow[c * 32 + q * 8]);
#pragma unroll
            for (int t = 0; t < 4; t++) {
                bf16x8 b = ld_frag(WfcT + (t * 16 + ln) * 64 + c * 32 + q * 8);
                accf[t] = __builtin_amdgcn_mfma_f32_16x16x32_bf16(a, b, accf[t], 0, 0, 0);
            }
        }
        __syncthreads();               // all waves done reading sB
        float* fB = (float*)sB;        // 64 rows x pitch 68 = 4352 floats = 17408 B
#pragma unroll
        for (int r = 0; r < 4; r++) {
            int nb = w * 16 + q * 4 + r;
#pragma unroll
            for (int t = 0; t < 4; t++) {
                int colI = t * 16 + ln;
                fB[nb * 68 + colI] = accf[t][r] + bfc[colI];
            }
        }
        __syncthreads();
#pragma unroll
        for (int i = 0; i < 4; i++) {
            int idx = i * 256 + tid;
            int row = idx >> 4, cc = idx & 15;
            int node = base + row;
            if (node < N)
                *(float4*)(fout + node * D + cc * 4) = *(const float4*)&fB[row * 68 + cc * 4];
        }
    } else {
        // coalesced writeback of this wave's 16 rows (2 uint4 per thread)
#pragma unroll
        for (int i = 0; i < 2; i++) {
            int idx = i * 64 + lane;
            int row = w * 16 + (idx >> 3);
            int ch = idx & 7;
            int node = base + row;
            if (node < N)
                *(uint4*)(xb_out + node * D + ch * 8) = *(const uint4*)&sA[row * LPITCH + ch * 8];
        }
    }
}

extern "C" void kernel_launch(void* const* d_in, const int* in_sizes, int n_in,
                              void* d_out, int out_size, void* d_ws, size_t ws_size,
                              hipStream_t stream) {
    const float* x_in = (const float*)d_in[0];
    const int* e_src = (const int*)d_in[1];
    const int* e_dst = (const int*)d_in[2];
    const float* w_l = (const float*)d_in[3];
    const float* b_l = (const float*)d_in[4];
    const float* w_r = (const float*)d_in[5];
    const float* gam = (const float*)d_in[6];
    const float* bet = (const float*)d_in[7];
    const float* w_res = (const float*)d_in[8];
    const float* b_res = (const float*)d_in[9];
    const float* w_fc = (const float*)d_in[10];
    const float* b_fc = (const float*)d_in[11];
    float* out = (float*)d_out;

    const int N = in_sizes[0] / D;
    const int E = in_sizes[1];
    const int nbuck = ((N - 1) >> BSHIFT) + 1;   // 196 for N=100000 (<= 512)
    const int eper = (E + CHUNKS - 1) / CHUNKS;

    size_t o = 0;
    auto carve = [&](size_t bytes) {
        size_t cur = o;
        o += (bytes + 255) & ~(size_t)255;
        return (char*)d_ws + cur;
    };
    int* row_ptr = (int*)carve((size_t)(N + 1) * 4);
    float* inv_deg = (float*)carve((size_t)N * 4);
    int* colA = (int*)carve((size_t)E * 4);
    int* staging = (int*)carve((size_t)nbuck * CAPB * 4);
    int* gcnt = (int*)carve((size_t)nbuck * 4);
    u16* WtL = (u16*)carve(3 * 64 * 128 * 2);
    u16* WresT = (u16*)carve(64 * 64 * 2);
    u16* WfcT = (u16*)carve(64 * 64 * 2);
    u16* xbA = (u16*)carve((size_t)N * D * 2);
    u16* xbB = (u16*)carve((size_t)N * D * 2);

    // CSR build: binAB (hist + bulk-reserve + scatter, tails folded) -> binC (sort)
    hipMemsetAsync(gcnt, 0, (size_t)nbuck * 4, stream);
    binAB_kernel<<<CHUNKS, 512, 0, stream>>>(e_src, e_dst, E, gcnt, staging,
                                             x_in, xbA, N * D / 4,
                                             w_l, w_r, w_res, w_fc, WtL, WresT, WfcT,
                                             nbuck, eper);
    binC_kernel<<<nbuck, 1024, 0, stream>>>(staging, gcnt, row_ptr, inv_deg, colA,
                                            N, nbuck);

    int gridT = (N + 63) / 64;

    // layer 0: xbA -> xbB  (residual via w_res MFMA)
    layer_kernel<<<gridT, 256, 0, stream>>>(xbA, row_ptr, colA, inv_deg, WtL,
                                            b_l, gam, bet, WresT, b_res,
                                            WfcT, b_fc, xbB, out, N, 1, 0);
    // layer 1: xbB -> xbA
    layer_kernel<<<gridT, 256, 0, stream>>>(xbB, row_ptr, colA, inv_deg, WtL + 8192,
                                            b_l + 64, gam + 64, bet + 64, WresT, b_res,
                                            WfcT, b_fc, xbA, out, N, 0, 0);
    // layer 2 + fused fc: xbA -> out (f32)
    layer_kernel<<<gridT, 256, 0, stream>>>(xbA, row_ptr, colA, inv_deg, WtL + 16384,
                                            b_l + 128, gam + 128, bet + 128, WresT, b_res,
                                            WfcT, b_fc, xbB, out, N, 0, 1);
}